// Round 1
// baseline (536.805 us; speedup 1.0000x reference)
//
#include <hip/hip_runtime.h>

#define GH 31
#define GW 51
#define PADc 30
#define KS 61
#define NPTS (GH * GW) /* 1581 */

// -4*ln2
#define NEG4LN2 (-2.7725887222397812f)

__global__ __launch_bounds__(256) void kde_lines(const float* __restrict__ bboxes,
                                                 int NB,
                                                 float* __restrict__ grids) {
    const int b = blockIdx.x;
    const int tid = threadIdx.x;

    __shared__ float salf[NPTS];   // flat index g = xi*31 + yi
    __shared__ float tmp[NPTS];
    __shared__ float red[256];
    __shared__ float xsal[GW], ysal[GH];
    __shared__ float xpad[GW + 2 * PADc];  // 111
    __shared__ float ypad[GH + 2 * PADc];  // 91
    __shared__ float boxsh[4 * 32];

    for (int i = tid; i < NB * 4; i += 256) boxsh[i] = bboxes[b * NB * 4 + i];
    const float bias0 = (float)NB * (1.0f / ((float)KS * (float)KS));
    for (int g = tid; g < NPTS; g += 256) salf[g] = bias0;
    __syncthreads();

    for (int k = 0; k < NB; ++k) {
        const float x1 = boxsh[k * 4 + 0], y1 = boxsh[k * 4 + 1];
        const float x2 = boxsh[k * 4 + 2], y2 = boxsh[k * 4 + 3];
        const float w = x2 - x1, h = y2 - y1;
        const float cx = x1 + 0.5f * w, cy = y1 + 0.5f * h;
        const float iw = 1.0f / w, ih = 1.0f / h;
        float local = 0.0f;
        for (int g = tid; g < NPTS; g += 256) {
            const int xi = g / GH;
            const int yi = g - xi * GH;
            const float gx = (float)xi * (1920.0f / 50.0f);
            const float gy = (float)yi * (1080.0f / 30.0f);
            const float dx = cx - gx, dy = cy - gy;
            const float d = dx * dx * iw + dy * dy * ih;
            const float e = expf(-0.5f * d);
            tmp[g] = e;
            local += e;
        }
        red[tid] = local;
        __syncthreads();
        for (int s = 128; s > 0; s >>= 1) {
            if (tid < s) red[tid] += red[tid + s];
            __syncthreads();
        }
        const float scale = 1.0f / (1e-5f + red[0]);
        __syncthreads();
        for (int g = tid; g < NPTS; g += 256) salf[g] += tmp[g] * scale;
        __syncthreads();
    }

    // marginal sums (global normalization of salf is scale-invariant in ox/wx, skipped)
    if (tid < GW) {
        float s = 0.0f;
        for (int yi = 0; yi < GH; ++yi) s += salf[tid * GH + yi];
        xsal[tid] = s;
    } else if (tid >= 64 && tid < 64 + GH) {
        const int yi = tid - 64;
        float s = 0.0f;
        for (int xi = 0; xi < GW; ++xi) s += salf[xi * GH + yi];
        ysal[yi] = s;
    }
    __syncthreads();

    // reflect pad (numpy 'reflect': no edge duplication; PAD <= n-1 so one fold)
    for (int p = tid; p < GW + 2 * PADc; p += 256) {
        int q = p - PADc;
        if (q < 0) q = -q;
        if (q > GW - 1) q = 2 * (GW - 1) - q;
        xpad[p] = xsal[q];
    }
    for (int p = tid; p < GH + 2 * PADc; p += 256) {
        int q = p - PADc;
        if (q < 0) q = -q;
        if (q > GH - 1) q = 2 * (GH - 1) - q;
        ypad[p] = ysal[q];
    }
    __syncthreads();

    float* og = grids + b * 128;  // [0..50] xgrid, [64..94] ygrid
    if (tid < GW) {
        float wx = 0.0f, ox = 0.0f;
        for (int k2 = 0; k2 < KS; ++k2) {
            const float dk = (float)(k2 - 30);
            const float f = expf(NEG4LN2 * dk * dk * (1.0f / 169.0f));
            const float v = xpad[tid + k2];
            wx += v * f;
            const float P = (float)(tid + k2 - 30) * (1.0f / 50.0f);
            ox += P * v * f;
        }
        float g = ox / wx * 2.0f - 1.0f;
        g = fminf(1.0f, fmaxf(-1.0f, g));
        og[tid] = g;
    } else if (tid >= 64 && tid < 64 + GH) {
        const int j = tid - 64;
        float wy = 0.0f, oy = 0.0f;
        for (int k2 = 0; k2 < KS; ++k2) {
            const float dk = (float)(k2 - 30);
            const float f = expf(NEG4LN2 * dk * dk * (1.0f / 169.0f));
            const float v = ypad[j + k2];
            wy += v * f;
            const float P = (float)(j + k2 - 30) * (1.0f / 30.0f);
            oy += P * v * f;
        }
        float g = oy / wy * 2.0f - 1.0f;
        g = fminf(1.0f, fmaxf(-1.0f, g));
        og[64 + j] = g;
    }
}

// out[b][y][x][2] as float4 = (x@2i, y, x@2i+1, y); one float4 per thread.
__global__ __launch_bounds__(256) void kde_fill(const float* __restrict__ grids,
                                                float4* __restrict__ out, int N4) {
    const int idx = blockIdx.x * 256 + threadIdx.x;
    if (idx >= N4) return;
    const int i = idx % 960;          // float4 within row (2 pixels each)
    const int row = idx / 960;        // b*1080 + y
    const int y = row % 1080;
    const int b = row / 1080;
    const float* og = grids + b * 128;

    // y interpolation (align_corners): fy = y * 30/1079
    const float fy = (float)y * (30.0f / 1079.0f);
    int y0 = (int)fy;
    if (y0 > GH - 1) y0 = GH - 1;
    int y1i = y0 + 1;
    if (y1i > GH - 1) y1i = GH - 1;
    const float ty = fy - (float)y0;
    const float yv = og[64 + y0] * (1.0f - ty) + og[64 + y1i] * ty;

    float xv[2];
#pragma unroll
    for (int p = 0; p < 2; ++p) {
        const int xo = 2 * i + p;
        const float fx = (float)xo * (50.0f / 1919.0f);
        int x0 = (int)fx;
        if (x0 > GW - 1) x0 = GW - 1;
        int x1i = x0 + 1;
        if (x1i > GW - 1) x1i = GW - 1;
        const float tx = fx - (float)x0;
        xv[p] = og[x0] * (1.0f - tx) + og[x1i] * tx;
    }
    out[idx] = make_float4(xv[0], yv, xv[1], yv);
}

extern "C" void kernel_launch(void* const* d_in, const int* in_sizes, int n_in,
                              void* d_out, int out_size, void* d_ws, size_t ws_size,
                              hipStream_t stream) {
    const float* bboxes = (const float*)d_in[1];
    float* out = (float*)d_out;
    const int B = out_size / (1080 * 1920 * 2);
    const int NB = in_sizes[1] / (B * 4);
    float* grids = (float*)d_ws;  // B * 128 floats

    kde_lines<<<B, 256, 0, stream>>>(bboxes, NB, grids);

    const int N4 = out_size / 4;
    kde_fill<<<(N4 + 255) / 256, 256, 0, stream>>>(grids, (float4*)out, N4);
}

// Round 2
// 507.584 us; speedup vs baseline: 1.0576x; 1.0576x over previous
//
#include <hip/hip_runtime.h>

#define GH 31
#define GW 51
#define PADc 30
#define KS 61
#define NPTS (GH * GW) /* 1581 */

// -4*ln2
#define NEG4LN2 (-2.7725887222397812f)

__device__ __forceinline__ float wave_sum64(float v) {
#pragma unroll
    for (int off = 32; off > 0; off >>= 1) v += __shfl_xor(v, off, 64);
    return v;
}

// Separable fast path: one block of 128 threads (2 waves) per batch.
// wave0 handles the x-axis (51 cols), wave1 the y-axis (31 rows).
template <int NBc>
__global__ __launch_bounds__(128) void kde_lines_sep(const float* __restrict__ bboxes,
                                                     float* __restrict__ grids) {
    const int b = blockIdx.x;
    const int tid = threadIdx.x;
    const int lane = tid & 63;
    const int wv = tid >> 6;

    __shared__ float boxsh[NBc * 4];
    __shared__ float SxA[NBc], SyA[NBc];
    __shared__ float xsal[GW], ysal[GH];
    __shared__ float xpad[GW + 2 * PADc];  // 111
    __shared__ float ypad[GH + 2 * PADc];  // 91

    if (tid < NBc * 4) boxsh[tid] = bboxes[b * NBc * 4 + tid];
    __syncthreads();

    float e[NBc];  // per-lane 1-D gaussian value for each box (registers; NBc unrolled)
    if (wv == 0) {
        const float gx = (float)lane * (1920.0f / 50.0f);
#pragma unroll
        for (int k = 0; k < NBc; ++k) {
            const float x1 = boxsh[4 * k + 0], x2 = boxsh[4 * k + 2];
            const float w = x2 - x1;
            const float cx = x1 + 0.5f * w;
            const float dx = cx - gx;
            const float ex = (lane < GW) ? expf(-0.5f * dx * dx / w) : 0.0f;
            e[k] = ex;
            const float s = wave_sum64(ex);
            if (lane == 0) SxA[k] = s;
        }
    } else {
        const float gy = (float)lane * (1080.0f / 30.0f);
#pragma unroll
        for (int k = 0; k < NBc; ++k) {
            const float y1 = boxsh[4 * k + 1], y2 = boxsh[4 * k + 3];
            const float h = y2 - y1;
            const float cy = y1 + 0.5f * h;
            const float dy = cy - gy;
            const float ey = (lane < GH) ? expf(-0.5f * dy * dy / h) : 0.0f;
            e[k] = ey;
            const float s = wave_sum64(ey);
            if (lane == 0) SyA[k] = s;
        }
    }
    __syncthreads();

    const float ubias = (float)NBc * (1.0f / ((float)KS * (float)KS));
    if (wv == 0) {
        if (lane < GW) {
            float xs = (float)GH * ubias;
#pragma unroll
            for (int k = 0; k < NBc; ++k) {
                const float sy = SyA[k];
                xs += e[k] * sy / (1e-5f + SxA[k] * sy);
            }
            xsal[lane] = xs;
        }
    } else {
        if (lane < GH) {
            float ys_ = (float)GW * ubias;
#pragma unroll
            for (int k = 0; k < NBc; ++k) {
                const float sx = SxA[k];
                ys_ += e[k] * sx / (1e-5f + sx * SyA[k]);
            }
            ysal[lane] = ys_;
        }
    }
    __syncthreads();

    // reflect pad (numpy 'reflect': no edge duplication; PAD <= n-1 so one fold)
    for (int p = tid; p < GW + 2 * PADc; p += 128) {
        int q = p - PADc;
        if (q < 0) q = -q;
        if (q > GW - 1) q = 2 * (GW - 1) - q;
        xpad[p] = xsal[q];
    }
    for (int p = tid; p < GH + 2 * PADc; p += 128) {
        int q = p - PADc;
        if (q < 0) q = -q;
        if (q > GH - 1) q = 2 * (GH - 1) - q;
        ypad[p] = ysal[q];
    }
    __syncthreads();

    float* og = grids + b * 128;  // [0..50] xgrid, [64..94] ygrid
    if (wv == 0 && lane < GW) {
        float wx = 0.0f, ox = 0.0f;
        for (int k2 = 0; k2 < KS; ++k2) {
            const float dk = (float)(k2 - 30);
            const float f = expf(NEG4LN2 * dk * dk * (1.0f / 169.0f));
            const float v = xpad[lane + k2];
            wx += v * f;
            const float P = (float)(lane + k2 - 30) * (1.0f / 50.0f);
            ox += P * v * f;
        }
        float g = ox / wx * 2.0f - 1.0f;
        g = fminf(1.0f, fmaxf(-1.0f, g));
        og[lane] = g;
    } else if (wv == 1 && lane < GH) {
        float wy = 0.0f, oy = 0.0f;
        for (int k2 = 0; k2 < KS; ++k2) {
            const float dk = (float)(k2 - 30);
            const float f = expf(NEG4LN2 * dk * dk * (1.0f / 169.0f));
            const float v = ypad[lane + k2];
            wy += v * f;
            const float P = (float)(lane + k2 - 30) * (1.0f / 30.0f);
            oy += P * v * f;
        }
        float g = oy / wy * 2.0f - 1.0f;
        g = fminf(1.0f, fmaxf(-1.0f, g));
        og[64 + lane] = g;
    }
}

// Generic fallback (round-1 algorithm) for NB != 20, NB <= 32.
__global__ __launch_bounds__(256) void kde_lines_generic(const float* __restrict__ bboxes,
                                                         int NB,
                                                         float* __restrict__ grids) {
    const int b = blockIdx.x;
    const int tid = threadIdx.x;

    __shared__ float salf[NPTS];
    __shared__ float tmp[NPTS];
    __shared__ float red[256];
    __shared__ float xsal[GW], ysal[GH];
    __shared__ float xpad[GW + 2 * PADc];
    __shared__ float ypad[GH + 2 * PADc];
    __shared__ float boxsh[4 * 32];

    for (int i = tid; i < NB * 4; i += 256) boxsh[i] = bboxes[b * NB * 4 + i];
    const float bias0 = (float)NB * (1.0f / ((float)KS * (float)KS));
    for (int g = tid; g < NPTS; g += 256) salf[g] = bias0;
    __syncthreads();

    for (int k = 0; k < NB; ++k) {
        const float x1 = boxsh[k * 4 + 0], y1 = boxsh[k * 4 + 1];
        const float x2 = boxsh[k * 4 + 2], y2 = boxsh[k * 4 + 3];
        const float w = x2 - x1, h = y2 - y1;
        const float cx = x1 + 0.5f * w, cy = y1 + 0.5f * h;
        const float iw = 1.0f / w, ih = 1.0f / h;
        float local = 0.0f;
        for (int g = tid; g < NPTS; g += 256) {
            const int xi = g / GH;
            const int yi = g - xi * GH;
            const float gx = (float)xi * (1920.0f / 50.0f);
            const float gy = (float)yi * (1080.0f / 30.0f);
            const float dx = cx - gx, dy = cy - gy;
            const float d = dx * dx * iw + dy * dy * ih;
            const float ev = expf(-0.5f * d);
            tmp[g] = ev;
            local += ev;
        }
        red[tid] = local;
        __syncthreads();
        for (int s = 128; s > 0; s >>= 1) {
            if (tid < s) red[tid] += red[tid + s];
            __syncthreads();
        }
        const float scale = 1.0f / (1e-5f + red[0]);
        __syncthreads();
        for (int g = tid; g < NPTS; g += 256) salf[g] += tmp[g] * scale;
        __syncthreads();
    }

    if (tid < GW) {
        float s = 0.0f;
        for (int yi = 0; yi < GH; ++yi) s += salf[tid * GH + yi];
        xsal[tid] = s;
    } else if (tid >= 64 && tid < 64 + GH) {
        const int yi = tid - 64;
        float s = 0.0f;
        for (int xi = 0; xi < GW; ++xi) s += salf[xi * GH + yi];
        ysal[yi] = s;
    }
    __syncthreads();

    for (int p = tid; p < GW + 2 * PADc; p += 256) {
        int q = p - PADc;
        if (q < 0) q = -q;
        if (q > GW - 1) q = 2 * (GW - 1) - q;
        xpad[p] = xsal[q];
    }
    for (int p = tid; p < GH + 2 * PADc; p += 256) {
        int q = p - PADc;
        if (q < 0) q = -q;
        if (q > GH - 1) q = 2 * (GH - 1) - q;
        ypad[p] = ysal[q];
    }
    __syncthreads();

    float* og = grids + b * 128;
    if (tid < GW) {
        float wx = 0.0f, ox = 0.0f;
        for (int k2 = 0; k2 < KS; ++k2) {
            const float dk = (float)(k2 - 30);
            const float f = expf(NEG4LN2 * dk * dk * (1.0f / 169.0f));
            const float v = xpad[tid + k2];
            wx += v * f;
            const float P = (float)(tid + k2 - 30) * (1.0f / 50.0f);
            ox += P * v * f;
        }
        float g = ox / wx * 2.0f - 1.0f;
        g = fminf(1.0f, fmaxf(-1.0f, g));
        og[tid] = g;
    } else if (tid >= 64 && tid < 64 + GH) {
        const int j = tid - 64;
        float wy = 0.0f, oy = 0.0f;
        for (int k2 = 0; k2 < KS; ++k2) {
            const float dk = (float)(k2 - 30);
            const float f = expf(NEG4LN2 * dk * dk * (1.0f / 169.0f));
            const float v = ypad[j + k2];
            wy += v * f;
            const float P = (float)(j + k2 - 30) * (1.0f / 30.0f);
            oy += P * v * f;
        }
        float g = oy / wy * 2.0f - 1.0f;
        g = fminf(1.0f, fmaxf(-1.0f, g));
        og[64 + j] = g;
    }
}

// out[b][y][x][2] as float4 = (x@2i, y, x@2i+1, y); one float4 per thread.
__global__ __launch_bounds__(256) void kde_fill(const float* __restrict__ grids,
                                                float4* __restrict__ out, int N4) {
    const int idx = blockIdx.x * 256 + threadIdx.x;
    if (idx >= N4) return;
    const int i = idx % 960;          // float4 within row (2 pixels each)
    const int row = idx / 960;        // b*1080 + y
    const int y = row % 1080;
    const int b = row / 1080;
    const float* og = grids + b * 128;

    const float fy = (float)y * (30.0f / 1079.0f);
    int y0 = (int)fy;
    if (y0 > GH - 1) y0 = GH - 1;
    int y1i = y0 + 1;
    if (y1i > GH - 1) y1i = GH - 1;
    const float ty = fy - (float)y0;
    const float yv = og[64 + y0] * (1.0f - ty) + og[64 + y1i] * ty;

    float xv[2];
#pragma unroll
    for (int p = 0; p < 2; ++p) {
        const int xo = 2 * i + p;
        const float fx = (float)xo * (50.0f / 1919.0f);
        int x0 = (int)fx;
        if (x0 > GW - 1) x0 = GW - 1;
        int x1i = x0 + 1;
        if (x1i > GW - 1) x1i = GW - 1;
        const float tx = fx - (float)x0;
        xv[p] = og[x0] * (1.0f - tx) + og[x1i] * tx;
    }
    out[idx] = make_float4(xv[0], yv, xv[1], yv);
}

extern "C" void kernel_launch(void* const* d_in, const int* in_sizes, int n_in,
                              void* d_out, int out_size, void* d_ws, size_t ws_size,
                              hipStream_t stream) {
    const float* bboxes = (const float*)d_in[1];
    float* out = (float*)d_out;
    const int B = out_size / (1080 * 1920 * 2);
    const int NB = in_sizes[1] / (B * 4);
    float* grids = (float*)d_ws;  // B * 128 floats

    if (NB == 20) {
        kde_lines_sep<20><<<B, 128, 0, stream>>>(bboxes, grids);
    } else {
        kde_lines_generic<<<B, 256, 0, stream>>>(bboxes, NB, grids);
    }

    const int N4 = out_size / 4;
    kde_fill<<<(N4 + 255) / 256, 256, 0, stream>>>(grids, (float4*)out, N4);
}